// Round 14
// baseline (516.405 us; speedup 1.0000x reference)
//
#include <hip/hip_runtime.h>

#define FP8_MAX 448.0f
#define EPSF 1e-12f

#define BM 256
#define BN 256
#define BK 32

typedef __attribute__((ext_vector_type(8))) _Float16 half8;
typedef __attribute__((ext_vector_type(4))) float floatx4;

#define VMCNT(n) asm volatile("s_waitcnt vmcnt(" #n ")" ::: "memory")

__device__ inline void async_copy16(const void* gp, void* lp) {
  __builtin_amdgcn_global_load_lds(
      (const __attribute__((address_space(1))) unsigned int*)gp,
      (__attribute__((address_space(3))) unsigned int*)lp,
      16, 0, 0);
}

// -------- fused absmax of two tensors: out[0]=max|a|, out[1]=max|b| -------
__global__ void absmax2_kernel(const float* __restrict__ a, int n4a,
                               const float* __restrict__ b, int n4b,
                               int blocks_a, unsigned* __restrict__ out) {
  const bool isA = (int)blockIdx.x < blocks_a;
  const float4* in4 = (const float4*)(isA ? a : b);
  const int n4 = isA ? n4a : n4b;
  const int nblk = isA ? blocks_a : (gridDim.x - blocks_a);
  const int bid = isA ? blockIdx.x : (blockIdx.x - blocks_a);
  int tid = bid * blockDim.x + threadIdx.x;
  int stride = nblk * blockDim.x;
  float m = 0.f;
  for (int i = tid; i < n4; i += stride) {
    float4 v = in4[i];
    m = fmaxf(m, fmaxf(fmaxf(fabsf(v.x), fabsf(v.y)),
                       fmaxf(fabsf(v.z), fabsf(v.w))));
  }
  for (int off = 32; off > 0; off >>= 1)
    m = fmaxf(m, __shfl_down(m, off, 64));
  __shared__ float smax[4];
  int lane = threadIdx.x & 63, w = threadIdx.x >> 6;
  if (lane == 0) smax[w] = m;
  __syncthreads();
  if (threadIdx.x == 0) {
    float bm = fmaxf(fmaxf(smax[0], smax[1]), fmaxf(smax[2], smax[3]));
    atomicMax(out + (isA ? 0 : 1), __float_as_uint(bm));
  }
}

// -------- fused quantize of two tensors: fp32 -> fp16 ints in [-448,448] --
__global__ void quant2_kernel(const float* __restrict__ a, int n8a,
                              const float* __restrict__ b, int n8b,
                              int blocks_a, _Float16* __restrict__ qa,
                              _Float16* __restrict__ qb,
                              const unsigned* __restrict__ amax_bits) {
  const bool isA = (int)blockIdx.x < blocks_a;
  const float4* in4 = (const float4*)(isA ? a : b);
  half8* out8 = (half8*)(isA ? qa : qb);
  const int n8 = isA ? n8a : n8b;
  const int nblk = isA ? blocks_a : (gridDim.x - blocks_a);
  const int bid = isA ? blockIdx.x : (blockIdx.x - blocks_a);
  const float scale =
      fmaxf(__uint_as_float(amax_bits[isA ? 0 : 1]) / FP8_MAX, EPSF);
  int tid = bid * blockDim.x + threadIdx.x;
  int stride = nblk * blockDim.x;
  for (int i = tid; i < n8; i += stride) {
    float4 va = in4[2 * i], vb = in4[2 * i + 1];
    half8 h;
    h[0] = (_Float16)rintf(fminf(fmaxf(va.x / scale, -FP8_MAX), FP8_MAX));
    h[1] = (_Float16)rintf(fminf(fmaxf(va.y / scale, -FP8_MAX), FP8_MAX));
    h[2] = (_Float16)rintf(fminf(fmaxf(va.z / scale, -FP8_MAX), FP8_MAX));
    h[3] = (_Float16)rintf(fminf(fmaxf(va.w / scale, -FP8_MAX), FP8_MAX));
    h[4] = (_Float16)rintf(fminf(fmaxf(vb.x / scale, -FP8_MAX), FP8_MAX));
    h[5] = (_Float16)rintf(fminf(fmaxf(vb.y / scale, -FP8_MAX), FP8_MAX));
    h[6] = (_Float16)rintf(fminf(fmaxf(vb.z / scale, -FP8_MAX), FP8_MAX));
    h[7] = (_Float16)rintf(fminf(fmaxf(vb.w / scale, -FP8_MAX), FP8_MAX));
    out8[i] = h;
  }
}

// -------- 256x256 NT GEMM, BK=32: A via LDS (4-deep), B DIRECT global->reg
// 8 waves (2M x 4N). LDS = 4 bufs x A-only 16 KiB = 64 KiB, 1 block/CU.
// DS traffic/tile drops 96->64 KB (B's 2x LDS amplification removed);
// B-frags ride the VMEM queue (overlaps the DS pipe), prefetched 1 tile
// ahead into registers, pinned by VMCNT "memory" clobber + one
// sched_barrier(0)/tile before the MFMA cluster.
// bn-clustered XCD swizzle: co-resident blocks on an XCD share bn ->
// B-panel (2 MB) L2-hot; A+B fit L3 entirely.
// Per tile t: {loadB(t+1) global; readFrags A(t+1) ds; stageA(t+3);
//   sched_barrier(0); 32 MFMA (all-reg); VMCNT(6); s_barrier}.
// Ledger: VMCNT(6) leaves exactly {loadB(t+1) 4, stageA(t+3) 2} in flight;
// stageA(t+1) drained at t-1 + published by its barrier before its reads;
// stageA(t+3) writes buf[(t-1)&3], last read at t-2, published end-of-(t-2).
// Tail: t=nt-3/nt-2 -> VMCNT(4); t=nt-1 -> VMCNT(0).
__global__ __launch_bounds__(512, 1) void gemm8_kernel(
    const _Float16* __restrict__ A,  // [M][K]
    const _Float16* __restrict__ B,  // [N][K]
    const float* __restrict__ bias, const unsigned* __restrict__ amax,
    float* __restrict__ C,  // [M][N]
    int M, int N, int K) {
  __shared__ __align__(16) _Float16 As[4][BM * BK];

  const int tid = threadIdx.x;
  const int w = tid >> 6;
  const int lane = tid & 63;
  const int wr = w >> 2;  // 0..1
  const int wc = w & 3;   // 0..3

  // bn-clustered XCD swizzle (requires nbn%8==0): xcd=bid%8 handles
  // bn in {xcd, xcd+8, ...}; within, sweep bm -> same-bn blocks co-resident.
  const int nbm = M / BM;
  const int bm = (blockIdx.x >> 3) % nbm;
  const int bn = (blockIdx.x & 7) + 8 * ((blockIdx.x >> 3) / nbm);

  const _Float16* Ab = A + (size_t)bm * BM * K;

  // A staging: per instr a wave covers 16 rows x 32 elems (1024B). Lane l:
  // row_rel = l>>2, LDS granule l&3; fetch DATA granule (l&3)^((l>>3)&3).
  const int gd8 = ((lane & 3) ^ ((lane >> 3) & 3)) * 8;
  const _Float16* Ag = Ab + (size_t)(lane >> 2) * K + gd8;

  auto stageA = [&](int kt) {  // 2 instrs: rows w*16 and 128+w*16
#pragma unroll
    for (int r = 0; r < 2; ++r) {
      const int R0 = r * 128 + w * 16;
      async_copy16(Ag + (size_t)R0 * K + kt * BK,
                   (void*)&As[kt & 3][R0 * BK]);
    }
  };

  // A read geometry: frag row = base16 + lr; granule = hi ^ ((lr>>1)&3)
  const int lr = lane & 15;
  const int hi = lane >> 4;  // 0..3
  const int gsw = (hi ^ ((lr >> 1) & 3)) * 8;
  const int aoff = (wr * 128 + lr) * BK + gsw;

  // B direct-from-global fragment base: row = bn*256 + wc*64 + n*16 + lr,
  // k = t*32 + hi*8. Per instr: 16 rows x one 64B line each.
  const _Float16* Bgf = B + (size_t)(bn * BN + wc * 64 + lr) * K + hi * 8;

  half8 afA[8], afB[8], bgA[4], bgB[4];
  floatx4 acc[8][4] = {};
  const int nt = K / BK;

  auto readFrags = [&](int kt, half8 (&af)[8]) {
    const _Float16* Asb = &As[kt & 3][0];
#pragma unroll
    for (int m = 0; m < 8; ++m)
      af[m] = *(const half8*)&Asb[aoff + m * 16 * BK];
  };
  auto loadB = [&](int kt, half8 (&bg)[4]) {
#pragma unroll
    for (int n = 0; n < 4; ++n)
      bg[n] = *(const half8*)(Bgf + (size_t)(n * 16) * K + (size_t)kt * BK);
  };
  auto mfmaAll = [&](half8 (&af)[8], half8 (&bg)[4]) {
    __builtin_amdgcn_s_setprio(1);
#pragma unroll
    for (int m = 0; m < 8; ++m)
#pragma unroll
      for (int n = 0; n < 4; ++n)
        acc[m][n] = __builtin_amdgcn_mfma_f32_16x16x32_f16(
            af[m], bg[n], acc[m][n], 0, 0, 0);
    __builtin_amdgcn_s_setprio(0);
  };

  // ---- prologue: A tiles 0,1 + B(0) + A tile2 (A(2) newest, left flying);
  // VMCNT(2) -> A(0),A(1),B(0) landed; barrier; read tile0 A-frags.
  stageA(0); stageA(1);
  loadB(0, bgA);
  stageA(2);
  VMCNT(2);
  __builtin_amdgcn_s_barrier();
  readFrags(0, afA);

  for (int t = 0; t < nt; t += 2) {
    // ---- even tile t: consume {afA,bgA}; prefetch into {afB,bgB}
    if (t + 1 < nt) { loadB(t + 1, bgB); readFrags(t + 1, afB); }
    if (t + 3 < nt) stageA(t + 3);
    __builtin_amdgcn_sched_barrier(0);  // pin prefetch before MFMA cluster
    mfmaAll(afA, bgA);
    if (t + 3 < nt) { VMCNT(6); }
    else if (t + 1 < nt) { VMCNT(4); }
    else { VMCNT(0); }
    __builtin_amdgcn_s_barrier();

    // ---- odd tile t+1: consume {afB,bgB}; prefetch into {afA,bgA}
    if (t + 2 < nt) { loadB(t + 2, bgA); readFrags(t + 2, afA); }
    if (t + 4 < nt) stageA(t + 4);
    __builtin_amdgcn_sched_barrier(0);
    mfmaAll(afB, bgB);
    if (t + 4 < nt) { VMCNT(6); }
    else if (t + 2 < nt) { VMCNT(4); }
    else { VMCNT(0); }
    __builtin_amdgcn_s_barrier();
  }

  // ---- epilogue: dequant + bias. C/D: col=lane&15, row=(lane>>4)*4+reg
  const float sx = fmaxf(__uint_as_float(amax[0]) / FP8_MAX, EPSF);
  const float sw = fmaxf(__uint_as_float(amax[1]) / FP8_MAX, EPSF);
  const float s = sx * sw;

  const int row0 = bm * BM + wr * 128 + hi * 4;
  const int col0 = bn * BN + wc * 64 + lr;
  float bv[4];
#pragma unroll
  for (int n = 0; n < 4; ++n) bv[n] = bias[col0 + n * 16];

#pragma unroll
  for (int m = 0; m < 8; ++m) {
#pragma unroll
    for (int n = 0; n < 4; ++n) {
      const size_t base = (size_t)(row0 + m * 16) * N + col0 + n * 16;
#pragma unroll
      for (int r = 0; r < 4; ++r)
        C[base + (size_t)r * N] = acc[m][n][r] * s + bv[n];
    }
  }
}

extern "C" void kernel_launch(void* const* d_in, const int* in_sizes, int n_in,
                              void* d_out, int out_size, void* d_ws,
                              size_t ws_size, hipStream_t stream) {
  const float* x = (const float*)d_in[0];
  const float* wgt = (const float*)d_in[1];
  const float* bias = (const float*)d_in[2];
  float* out = (float*)d_out;

  const int N = in_sizes[2];      // out features (4096)
  const int K = in_sizes[1] / N;  // in features (4096)
  const int M = in_sizes[0] / K;  // rows (8192)

  unsigned* amax = (unsigned*)d_ws;
  _Float16* xq = (_Float16*)((char*)d_ws + 256);
  _Float16* wq =
      (_Float16*)((char*)d_ws + 256 + (size_t)M * K * sizeof(_Float16));

  hipMemsetAsync(d_ws, 0, 8, stream);
  absmax2_kernel<<<3072, 256, 0, stream>>>(x, M * K / 4, wgt, N * K / 4, 2048,
                                           amax);
  quant2_kernel<<<3072, 256, 0, stream>>>(x, M * K / 8, wgt, N * K / 8, 2048,
                                          xq, wq, amax);

  gemm8_kernel<<<dim3((M / BM) * (N / BN)), 512, 0, stream>>>(
      xq, wq, bias, amax, out, M, N, K);
}

// Round 15
// 355.583 us; speedup vs baseline: 1.4523x; 1.4523x over previous
//
#include <hip/hip_runtime.h>

#define FP8_MAX 448.0f
#define EPSF 1e-12f

#define BM 256
#define BN 256
#define BK 32

typedef __attribute__((ext_vector_type(8))) _Float16 half8;
typedef __attribute__((ext_vector_type(4))) float floatx4;

#define VMCNT(n) asm volatile("s_waitcnt vmcnt(" #n ")" ::: "memory")
// rule #18: counted lgkm wait + sched_barrier(0) so MFMAs can't hoist past
#define LGKMW(n)                                                  \
  do {                                                            \
    asm volatile("s_waitcnt lgkmcnt(" #n ")" ::: "memory");       \
    __builtin_amdgcn_sched_barrier(0);                            \
  } while (0)
// pinned LDS read: volatile asm can't be sunk by the scheduler
#define DSR(dst, addr, imm)                       \
  asm volatile("ds_read_b128 %0, %1 offset:" #imm \
               : "=v"(dst)                        \
               : "v"(addr))

__device__ inline void async_copy16(const void* gp, void* lp) {
  __builtin_amdgcn_global_load_lds(
      (const __attribute__((address_space(1))) unsigned int*)gp,
      (__attribute__((address_space(3))) unsigned int*)lp,
      16, 0, 0);
}

// -------- fused absmax of two tensors: out[0]=max|a|, out[1]=max|b| -------
__global__ void absmax2_kernel(const float* __restrict__ a, int n4a,
                               const float* __restrict__ b, int n4b,
                               int blocks_a, unsigned* __restrict__ out) {
  const bool isA = (int)blockIdx.x < blocks_a;
  const float4* in4 = (const float4*)(isA ? a : b);
  const int n4 = isA ? n4a : n4b;
  const int nblk = isA ? blocks_a : (gridDim.x - blocks_a);
  const int bid = isA ? blockIdx.x : (blockIdx.x - blocks_a);
  int tid = bid * blockDim.x + threadIdx.x;
  int stride = nblk * blockDim.x;
  float m = 0.f;
  for (int i = tid; i < n4; i += stride) {
    float4 v = in4[i];
    m = fmaxf(m, fmaxf(fmaxf(fabsf(v.x), fabsf(v.y)),
                       fmaxf(fabsf(v.z), fabsf(v.w))));
  }
  for (int off = 32; off > 0; off >>= 1)
    m = fmaxf(m, __shfl_down(m, off, 64));
  __shared__ float smax[4];
  int lane = threadIdx.x & 63, w = threadIdx.x >> 6;
  if (lane == 0) smax[w] = m;
  __syncthreads();
  if (threadIdx.x == 0) {
    float bm = fmaxf(fmaxf(smax[0], smax[1]), fmaxf(smax[2], smax[3]));
    atomicMax(out + (isA ? 0 : 1), __float_as_uint(bm));
  }
}

// -------- fused quantize of two tensors: fp32 -> fp16 ints in [-448,448] --
__global__ void quant2_kernel(const float* __restrict__ a, int n8a,
                              const float* __restrict__ b, int n8b,
                              int blocks_a, _Float16* __restrict__ qa,
                              _Float16* __restrict__ qb,
                              const unsigned* __restrict__ amax_bits) {
  const bool isA = (int)blockIdx.x < blocks_a;
  const float4* in4 = (const float4*)(isA ? a : b);
  half8* out8 = (half8*)(isA ? qa : qb);
  const int n8 = isA ? n8a : n8b;
  const int nblk = isA ? blocks_a : (gridDim.x - blocks_a);
  const int bid = isA ? blockIdx.x : (blockIdx.x - blocks_a);
  const float scale =
      fmaxf(__uint_as_float(amax_bits[isA ? 0 : 1]) / FP8_MAX, EPSF);
  int tid = bid * blockDim.x + threadIdx.x;
  int stride = nblk * blockDim.x;
  for (int i = tid; i < n8; i += stride) {
    float4 va = in4[2 * i], vb = in4[2 * i + 1];
    half8 h;
    h[0] = (_Float16)rintf(fminf(fmaxf(va.x / scale, -FP8_MAX), FP8_MAX));
    h[1] = (_Float16)rintf(fminf(fmaxf(va.y / scale, -FP8_MAX), FP8_MAX));
    h[2] = (_Float16)rintf(fminf(fmaxf(va.z / scale, -FP8_MAX), FP8_MAX));
    h[3] = (_Float16)rintf(fminf(fmaxf(va.w / scale, -FP8_MAX), FP8_MAX));
    h[4] = (_Float16)rintf(fminf(fmaxf(vb.x / scale, -FP8_MAX), FP8_MAX));
    h[5] = (_Float16)rintf(fminf(fmaxf(vb.y / scale, -FP8_MAX), FP8_MAX));
    h[6] = (_Float16)rintf(fminf(fmaxf(vb.z / scale, -FP8_MAX), FP8_MAX));
    h[7] = (_Float16)rintf(fminf(fmaxf(vb.w / scale, -FP8_MAX), FP8_MAX));
    out8[i] = h;
  }
}

// -------- 256x256 NT GEMM, BK=32, 4-deep LDS rotation, ASM reg-prefetch ---
// R13 structure; the one change: tile t+1's 12 fragment reads are issued as
// inline-asm ds_read_b128 (volatile -> scheduler CANNOT sink them to uses,
// which R11/R13 showed it does for C++ loads). Consumption guarded by
// lgkmcnt(12): the 12 just-issued reads are the only ones allowed
// outstanding, and the DS queue is FIFO, so the consuming set (issued a
// full tile earlier) is retired. sched_barrier(0) pins the MFMAs after it.
// Ledger (verified R10-R13): VMCNT(4) at end of t leaves only stage(t+3)
// in flight => stage(t+1) landed before its reads at tile t (post-barrier);
// stage(t+3) writes buf[(t-1)&3] (≠ read-target (t+1)&3), last read at t-2,
// published by the end-of-(t-1) barrier. Tail: VMCNT(0) when staging stops.
__global__ __launch_bounds__(512, 1) void gemm8_kernel(
    const _Float16* __restrict__ A,  // [M][K]
    const _Float16* __restrict__ B,  // [N][K]
    const float* __restrict__ bias, const unsigned* __restrict__ amax,
    float* __restrict__ C,  // [M][N]
    int M, int N, int K) {
  __shared__ __align__(16) _Float16 As[4][BM * BK];
  __shared__ __align__(16) _Float16 Bs[4][BN * BK];

  const int tid = threadIdx.x;
  const int w = tid >> 6;
  const int lane = tid & 63;
  const int wr = w >> 2;  // 0..1
  const int wc = w & 3;   // 0..3

  // XCD-aware block swizzle (gridDim.x divisible by 8)
  const int nwg = gridDim.x;
  const int cpx = nwg >> 3;
  const int swz = (blockIdx.x & 7) * cpx + (blockIdx.x >> 3);
  const int nbn = N / BN;
  const int bm = swz / nbn;
  const int bn = swz % nbn;

  const _Float16* Ab = A + (size_t)bm * BM * K;
  const _Float16* Bb = B + (size_t)bn * BN * K;

  // staging: per instr a wave covers 16 rows x 32 elems (1024B). Lane l:
  // row_rel = l>>2, LDS granule l&3; fetch DATA granule (l&3)^((l>>3)&3).
  const int gd8 = ((lane & 3) ^ ((lane >> 3) & 3)) * 8;
  const _Float16* Ag = Ab + (size_t)(lane >> 2) * K + gd8;
  const _Float16* Bg = Bb + (size_t)(lane >> 2) * K + gd8;

  auto stage = [&](int kt) {  // 4 instrs: A rows {w*16, 128+w*16}, B same
#pragma unroll
    for (int r = 0; r < 2; ++r) {
      const int R0 = r * 128 + w * 16;
      async_copy16(Ag + (size_t)R0 * K + kt * BK,
                   (void*)&As[kt & 3][R0 * BK]);
    }
#pragma unroll
    for (int r = 0; r < 2; ++r) {
      const int R0 = r * 128 + w * 16;
      async_copy16(Bg + (size_t)R0 * K + kt * BK,
                   (void*)&Bs[kt & 3][R0 * BK]);
    }
  };

  // read geometry: frag row = base16 + lr; granule = hi ^ ((lr>>1)&3)
  const int lr = lane & 15;
  const int hi = lane >> 4;  // 0..3
  const int gsw = (hi ^ ((lr >> 1) & 3)) * 8;
  const unsigned asbase = (unsigned)(uintptr_t)&As[0][0];
  const unsigned bsbase = (unsigned)(uintptr_t)&Bs[0][0];
  const unsigned aoffb = (unsigned)(((wr * 128 + lr) * BK + gsw) * 2);
  const unsigned boffb = (unsigned)(((wc * 64 + lr) * BK + gsw) * 2);

  half8 afA[8], bfA[4], afB[8], bfB[4];
  floatx4 acc[8][4] = {};
  const int nt = K / BK;

  // pinned issue of one tile's 12 fragment reads (frag stride 16*BK*2=1024B)
#define ISSUE_READS(kt, af, bf)                              \
  do {                                                       \
    unsigned aaddr = asbase + ((kt) & 3) * 16384 + aoffb;    \
    unsigned baddr = bsbase + ((kt) & 3) * 16384 + boffb;    \
    DSR(af[0], aaddr, 0);                                    \
    DSR(af[1], aaddr, 1024);                                 \
    DSR(af[2], aaddr, 2048);                                 \
    DSR(af[3], aaddr, 3072);                                 \
    DSR(af[4], aaddr, 4096);                                 \
    DSR(af[5], aaddr, 5120);                                 \
    DSR(af[6], aaddr, 6144);                                 \
    DSR(af[7], aaddr, 7168);                                 \
    DSR(bf[0], baddr, 0);                                    \
    DSR(bf[1], baddr, 1024);                                 \
    DSR(bf[2], baddr, 2048);                                 \
    DSR(bf[3], baddr, 3072);                                 \
  } while (0)

  auto mfmaAll = [&](half8 (&af)[8], half8 (&bf)[4]) {
    __builtin_amdgcn_s_setprio(1);
#pragma unroll
    for (int m = 0; m < 8; ++m)
#pragma unroll
      for (int n = 0; n < 4; ++n)
        acc[m][n] = __builtin_amdgcn_mfma_f32_16x16x32_f16(
            af[m], bf[n], acc[m][n], 0, 0, 0);
    __builtin_amdgcn_s_setprio(0);
  };

  // ---- prologue: stage tiles 0,1,2; VMCNT(4) -> tiles 0,1 landed
  // (outstanding = stage(2)); barrier; issue tile0 reads into set A.
  stage(0); stage(1); stage(2);
  VMCNT(4);
  __builtin_amdgcn_s_barrier();
  ISSUE_READS(0, afA, bfA);

  for (int t = 0; t < nt; t += 2) {
    // ---- even tile t (t+1 always < nt): issue reads(t+1)->B; MFMA from A
    ISSUE_READS(t + 1, afB, bfB);
    if (t + 3 < nt) stage(t + 3);
    LGKMW(12);  // set A retired (FIFO; only the 12 new may be outstanding)
    mfmaAll(afA, bfA);
    if (t + 3 < nt) { VMCNT(4); } else { VMCNT(0); }
    __builtin_amdgcn_s_barrier();

    // ---- odd tile t+1: issue reads(t+2)->A (if any); MFMA from B
    if (t + 2 < nt) {
      ISSUE_READS(t + 2, afA, bfA);
      if (t + 4 < nt) stage(t + 4);
      LGKMW(12);
    } else {
      LGKMW(0);
    }
    mfmaAll(afB, bfB);
    if (t + 4 < nt) { VMCNT(4); } else { VMCNT(0); }
    __builtin_amdgcn_s_barrier();
  }

  // ---- epilogue: dequant + bias. C/D: col=lane&15, row=(lane>>4)*4+reg
  const float sx = fmaxf(__uint_as_float(amax[0]) / FP8_MAX, EPSF);
  const float sw = fmaxf(__uint_as_float(amax[1]) / FP8_MAX, EPSF);
  const float s = sx * sw;

  const int row0 = bm * BM + wr * 128 + hi * 4;
  const int col0 = bn * BN + wc * 64 + lr;
  float bv[4];
#pragma unroll
  for (int n = 0; n < 4; ++n) bv[n] = bias[col0 + n * 16];

#pragma unroll
  for (int m = 0; m < 8; ++m) {
#pragma unroll
    for (int n = 0; n < 4; ++n) {
      const size_t base = (size_t)(row0 + m * 16) * N + col0 + n * 16;
#pragma unroll
      for (int r = 0; r < 4; ++r)
        C[base + (size_t)r * N] = acc[m][n][r] * s + bv[n];
    }
  }
}

extern "C" void kernel_launch(void* const* d_in, const int* in_sizes, int n_in,
                              void* d_out, int out_size, void* d_ws,
                              size_t ws_size, hipStream_t stream) {
  const float* x = (const float*)d_in[0];
  const float* wgt = (const float*)d_in[1];
  const float* bias = (const float*)d_in[2];
  float* out = (float*)d_out;

  const int N = in_sizes[2];      // out features (4096)
  const int K = in_sizes[1] / N;  // in features (4096)
  const int M = in_sizes[0] / K;  // rows (8192)

  unsigned* amax = (unsigned*)d_ws;
  _Float16* xq = (_Float16*)((char*)d_ws + 256);
  _Float16* wq =
      (_Float16*)((char*)d_ws + 256 + (size_t)M * K * sizeof(_Float16));

  hipMemsetAsync(d_ws, 0, 8, stream);
  absmax2_kernel<<<3072, 256, 0, stream>>>(x, M * K / 4, wgt, N * K / 4, 2048,
                                           amax);
  quant2_kernel<<<3072, 256, 0, stream>>>(x, M * K / 8, wgt, N * K / 8, 2048,
                                          xq, wq, amax);

  gemm8_kernel<<<dim3((M / BM) * (N / BN)), 512, 0, stream>>>(
      xq, wq, bias, amax, out, M, N, K);
}

// Round 17
// 341.814 us; speedup vs baseline: 1.5108x; 1.0403x over previous
//
#include <hip/hip_runtime.h>

#define FP8_MAX 448.0f
#define EPSF 1e-12f

#define BM 256
#define BN 256
#define BK 32

typedef __attribute__((ext_vector_type(8))) _Float16 half8;
typedef __attribute__((ext_vector_type(4))) float floatx4;

#define VMCNT(n) asm volatile("s_waitcnt vmcnt(" #n ")" ::: "memory")

__device__ inline void async_copy16(const void* gp, void* lp) {
  __builtin_amdgcn_global_load_lds(
      (const __attribute__((address_space(1))) unsigned int*)gp,
      (__attribute__((address_space(3))) unsigned int*)lp,
      16, 0, 0);
}

// -------- fused absmax of two tensors: out[0]=max|a|, out[1]=max|b| -------
__global__ void absmax2_kernel(const float* __restrict__ a, int n4a,
                               const float* __restrict__ b, int n4b,
                               int blocks_a, unsigned* __restrict__ out) {
  const bool isA = (int)blockIdx.x < blocks_a;
  const float4* in4 = (const float4*)(isA ? a : b);
  const int n4 = isA ? n4a : n4b;
  const int nblk = isA ? blocks_a : (gridDim.x - blocks_a);
  const int bid = isA ? blockIdx.x : (blockIdx.x - blocks_a);
  int tid = bid * blockDim.x + threadIdx.x;
  int stride = nblk * blockDim.x;
  float m = 0.f;
  for (int i = tid; i < n4; i += stride) {
    float4 v = in4[i];
    m = fmaxf(m, fmaxf(fmaxf(fabsf(v.x), fabsf(v.y)),
                       fmaxf(fabsf(v.z), fabsf(v.w))));
  }
  for (int off = 32; off > 0; off >>= 1)
    m = fmaxf(m, __shfl_down(m, off, 64));
  __shared__ float smax[4];
  int lane = threadIdx.x & 63, w = threadIdx.x >> 6;
  if (lane == 0) smax[w] = m;
  __syncthreads();
  if (threadIdx.x == 0) {
    float bm = fmaxf(fmaxf(smax[0], smax[1]), fmaxf(smax[2], smax[3]));
    atomicMax(out + (isA ? 0 : 1), __float_as_uint(bm));
  }
}

// -------- fused quantize of two tensors: fp32 -> fp16 ints in [-448,448] --
__global__ void quant2_kernel(const float* __restrict__ a, int n8a,
                              const float* __restrict__ b, int n8b,
                              int blocks_a, _Float16* __restrict__ qa,
                              _Float16* __restrict__ qb,
                              const unsigned* __restrict__ amax_bits) {
  const bool isA = (int)blockIdx.x < blocks_a;
  const float4* in4 = (const float4*)(isA ? a : b);
  half8* out8 = (half8*)(isA ? qa : qb);
  const int n8 = isA ? n8a : n8b;
  const int nblk = isA ? blocks_a : (gridDim.x - blocks_a);
  const int bid = isA ? blockIdx.x : (blockIdx.x - blocks_a);
  const float scale =
      fmaxf(__uint_as_float(amax_bits[isA ? 0 : 1]) / FP8_MAX, EPSF);
  int tid = bid * blockDim.x + threadIdx.x;
  int stride = nblk * blockDim.x;
  for (int i = tid; i < n8; i += stride) {
    float4 va = in4[2 * i], vb = in4[2 * i + 1];
    half8 h;
    h[0] = (_Float16)rintf(fminf(fmaxf(va.x / scale, -FP8_MAX), FP8_MAX));
    h[1] = (_Float16)rintf(fminf(fmaxf(va.y / scale, -FP8_MAX), FP8_MAX));
    h[2] = (_Float16)rintf(fminf(fmaxf(va.z / scale, -FP8_MAX), FP8_MAX));
    h[3] = (_Float16)rintf(fminf(fmaxf(va.w / scale, -FP8_MAX), FP8_MAX));
    h[4] = (_Float16)rintf(fminf(fmaxf(vb.x / scale, -FP8_MAX), FP8_MAX));
    h[5] = (_Float16)rintf(fminf(fmaxf(vb.y / scale, -FP8_MAX), FP8_MAX));
    h[6] = (_Float16)rintf(fminf(fmaxf(vb.z / scale, -FP8_MAX), FP8_MAX));
    h[7] = (_Float16)rintf(fminf(fmaxf(vb.w / scale, -FP8_MAX), FP8_MAX));
    out8[i] = h;
  }
}

// -------- 256x256 NT GEMM, BK=32, 4-deep LDS rotation, reg-prefetch -------
// R13 structure (best verified: 249.5 µs GEMM, 1100 TF) + nontemporal C
// stores: with 512 blocks / 256 CUs each CU runs 2 sequential blocks;
// regular C stores (134 MB) thrash L2/L3 and evict round-2's A/B panels
// (FETCH_SIZE 296 MB vs 201 ideal). Nontemporal stores keep A/B resident.
// Per tile t (ONE barrier): issue 12 ds_reads of tile t+1's fragments
// (ping set) -> stage(t+3) -> 32 MFMA from pong set -> VMCNT(4) -> barrier.
// Ledger (verified R10-R15): VMCNT(4) at end of t leaves only stage(t+3)
// in flight => stage(t+1) landed before its reads during tile t;
// stage(t+3) writes buf[(t-1)&3], last read at t-2, published by the
// end-of-(t-1) barrier. Tail: VMCNT(0) once staging stops.
// Swizzle (BK=32, verified, 0 conflicts): staging pre-swizzles global
// granule (l&3)^((l>>3)&3) with linear LDS dest; read granule hi^((lr>>1)&3).
__global__ __launch_bounds__(512, 1) void gemm8_kernel(
    const _Float16* __restrict__ A,  // [M][K]
    const _Float16* __restrict__ B,  // [N][K]
    const float* __restrict__ bias, const unsigned* __restrict__ amax,
    float* __restrict__ C,  // [M][N]
    int M, int N, int K) {
  __shared__ __align__(16) _Float16 As[4][BM * BK];
  __shared__ __align__(16) _Float16 Bs[4][BN * BK];

  const int tid = threadIdx.x;
  const int w = tid >> 6;
  const int lane = tid & 63;
  const int wr = w >> 2;  // 0..1
  const int wc = w & 3;   // 0..3

  // XCD-aware block swizzle (gridDim.x divisible by 8)
  const int nwg = gridDim.x;
  const int cpx = nwg >> 3;
  const int swz = (blockIdx.x & 7) * cpx + (blockIdx.x >> 3);
  const int nbn = N / BN;
  const int bm = swz / nbn;
  const int bn = swz % nbn;

  const _Float16* Ab = A + (size_t)bm * BM * K;
  const _Float16* Bb = B + (size_t)bn * BN * K;

  // staging: per instr a wave covers 16 rows x 32 elems (1024B). Lane l:
  // row_rel = l>>2, LDS granule l&3; fetch DATA granule (l&3)^((l>>3)&3).
  const int gd8 = ((lane & 3) ^ ((lane >> 3) & 3)) * 8;
  const _Float16* Ag = Ab + (size_t)(lane >> 2) * K + gd8;
  const _Float16* Bg = Bb + (size_t)(lane >> 2) * K + gd8;

  auto stage = [&](int kt) {  // 4 instrs: A rows {w*16, 128+w*16}, B same
#pragma unroll
    for (int r = 0; r < 2; ++r) {
      const int R0 = r * 128 + w * 16;
      async_copy16(Ag + (size_t)R0 * K + kt * BK,
                   (void*)&As[kt & 3][R0 * BK]);
    }
#pragma unroll
    for (int r = 0; r < 2; ++r) {
      const int R0 = r * 128 + w * 16;
      async_copy16(Bg + (size_t)R0 * K + kt * BK,
                   (void*)&Bs[kt & 3][R0 * BK]);
    }
  };

  // read geometry: frag row = base16 + lr; granule = hi ^ ((lr>>1)&3)
  const int lr = lane & 15;
  const int hi = lane >> 4;  // 0..3
  const int gsw = (hi ^ ((lr >> 1) & 3)) * 8;
  const int aoff = (wr * 128 + lr) * BK + gsw;
  const int boff = (wc * 64 + lr) * BK + gsw;

  half8 afA[8], bfA[4], afB[8], bfB[4];
  floatx4 acc[8][4] = {};
  const int nt = K / BK;

  auto readFrags = [&](int kt, half8 (&af)[8], half8 (&bf)[4]) {
    const _Float16* Asb = &As[kt & 3][0];
    const _Float16* Bsb = &Bs[kt & 3][0];
#pragma unroll
    for (int m = 0; m < 8; ++m)
      af[m] = *(const half8*)&Asb[aoff + m * 16 * BK];
#pragma unroll
    for (int n = 0; n < 4; ++n)
      bf[n] = *(const half8*)&Bsb[boff + n * 16 * BK];
  };

  auto mfmaAll = [&](half8 (&af)[8], half8 (&bf)[4]) {
    __builtin_amdgcn_s_setprio(1);
#pragma unroll
    for (int m = 0; m < 8; ++m)
#pragma unroll
      for (int n = 0; n < 4; ++n)
        acc[m][n] = __builtin_amdgcn_mfma_f32_16x16x32_f16(
            af[m], bf[n], acc[m][n], 0, 0, 0);
    __builtin_amdgcn_s_setprio(0);
  };

  // ---- prologue: stage tiles 0,1,2; VMCNT(4) -> tiles 0,1 landed
  // (outstanding = stage(2)); barrier; read tile0 frags into set A.
  stage(0); stage(1); stage(2);
  VMCNT(4);
  __builtin_amdgcn_s_barrier();
  readFrags(0, afA, bfA);

  for (int t = 0; t < nt; t += 2) {
    // ---- even tile t: prefetch frags(t+1) into B; MFMA from A
    if (t + 1 < nt) readFrags(t + 1, afB, bfB);
    if (t + 3 < nt) stage(t + 3);
    mfmaAll(afA, bfA);
    if (t + 3 < nt) { VMCNT(4); } else { VMCNT(0); }
    __builtin_amdgcn_s_barrier();

    // ---- odd tile t+1: prefetch frags(t+2) into A; MFMA from B
    if (t + 2 < nt) readFrags(t + 2, afA, bfA);
    if (t + 4 < nt) stage(t + 4);
    mfmaAll(afB, bfB);
    if (t + 4 < nt) { VMCNT(4); } else { VMCNT(0); }
    __builtin_amdgcn_s_barrier();
  }

  // ---- epilogue: dequant + bias, NONTEMPORAL stores (C never re-read;
  // keeps A/B panels L2/L3-resident for the CU's second sequential block).
  const float sx = fmaxf(__uint_as_float(amax[0]) / FP8_MAX, EPSF);
  const float sw = fmaxf(__uint_as_float(amax[1]) / FP8_MAX, EPSF);
  const float s = sx * sw;

  const int row0 = bm * BM + wr * 128 + hi * 4;
  const int col0 = bn * BN + wc * 64 + lr;
  float bv[4];
#pragma unroll
  for (int n = 0; n < 4; ++n) bv[n] = bias[col0 + n * 16];

#pragma unroll
  for (int m = 0; m < 8; ++m) {
#pragma unroll
    for (int n = 0; n < 4; ++n) {
      const size_t base = (size_t)(row0 + m * 16) * N + col0 + n * 16;
#pragma unroll
      for (int r = 0; r < 4; ++r)
        __builtin_nontemporal_store(acc[m][n][r] * s + bv[n],
                                    &C[base + (size_t)r * N]);
    }
  }
}

extern "C" void kernel_launch(void* const* d_in, const int* in_sizes, int n_in,
                              void* d_out, int out_size, void* d_ws,
                              size_t ws_size, hipStream_t stream) {
  const float* x = (const float*)d_in[0];
  const float* wgt = (const float*)d_in[1];
  const float* bias = (const float*)d_in[2];
  float* out = (float*)d_out;

  const int N = in_sizes[2];      // out features (4096)
  const int K = in_sizes[1] / N;  // in features (4096)
  const int M = in_sizes[0] / K;  // rows (8192)

  unsigned* amax = (unsigned*)d_ws;
  _Float16* xq = (_Float16*)((char*)d_ws + 256);
  _Float16* wq =
      (_Float16*)((char*)d_ws + 256 + (size_t)M * K * sizeof(_Float16));

  hipMemsetAsync(d_ws, 0, 8, stream);
  absmax2_kernel<<<3072, 256, 0, stream>>>(x, M * K / 4, wgt, N * K / 4, 2048,
                                           amax);
  quant2_kernel<<<3072, 256, 0, stream>>>(x, M * K / 8, wgt, N * K / 8, 2048,
                                          xq, wq, amax);

  gemm8_kernel<<<dim3((M / BM) * (N / BN)), 512, 0, stream>>>(
      xq, wq, bias, amax, out, M, N, K);
}